// Round 17
// baseline (69.703 us; speedup 1.0000x reference)
//
#include <hip/hip_runtime.h>
#include <hip/hip_bf16.h>

typedef __bf16 bf16;
typedef __bf16 bf16x4 __attribute__((ext_vector_type(4)));
typedef __bf16 bf16x8 __attribute__((ext_vector_type(8)));
typedef float f32x4 __attribute__((ext_vector_type(4)));
typedef long i64;

// async global->LDS, 16B per lane. LDS dest must be wave-uniform (HW adds lane*16).
__device__ __forceinline__ void gload16(const void* g, void* l) {
  __builtin_amdgcn_global_load_lds(
      (const __attribute__((address_space(1))) unsigned int*)g,
      (__attribute__((address_space(3))) unsigned int*)l, 16, 0, 0);
}

// All intermediates fp8 e4m3, 64-B rows, 8-B granules, granule-XOR (row&7):
//  Pq/Pk: [bh][kb16][row c(256)][64 B]   (k-dim l)   value = P
//  Vt:    [bh][db4] [row l(1024)][64 B]  (k-dim d)   value = 8*V
//  Pattn: [bh][db4] [row c(256)][64 B]   (k-dim d)   value = 32*P
// PV accumulator rescale: 1/(8*32) = 1/256.

// ---------------- Kernel A: projections. x<128: k-pair, x<256: q-pair, else v.
// k/q path: ZERO LDS, ZERO barriers. Thread owns output granule (ch, kb, gcol)
// = 8 consecutive l of all 8 c-rows of its channel: reads its 2x64B input rows
// ONCE (coalesced), computes all 8 j outputs, 8 coalesced int2 stores.
__global__ __launch_bounds__(256) void proj_kqv(
    const float* __restrict__ kin, const float* __restrict__ qin,
    const float* __restrict__ vin,
    const float* __restrict__ wk, const float* __restrict__ bk,
    const float* __restrict__ wq, const float* __restrict__ bq,
    const float* __restrict__ wv, const float* __restrict__ bv,
    char* __restrict__ Pk, char* __restrict__ Pq, char* __restrict__ Vt) {
  int b = blockIdx.y;
  int x = blockIdx.x;
  int t = threadIdx.x;
  __shared__ __attribute__((aligned(16))) char smem[17152];  // v-path only
  if (x < 256) {
    bool isq = x >= 128;
    int g0 = (x & 127)*2;
    const float* in   = isq ? qin : kin;
    const float* w    = isq ? wq : wk;
    const float* bias = isq ? bq : bk;
    char* out         = isq ? Pq : Pk;
    int ch = t >> 7, kb = (t >> 3) & 15, gcol = t & 7;
    int g = g0 + ch;
    float4 wj[8]; float bj[8];
#pragma unroll
    for (int j = 0; j < 8; j++) {
      wj[j] = reinterpret_cast<const float4*>(w)[g*8 + j];
      bj[j] = bias[g*8 + j];
    }
    const char* chg = (const char*)(in + ((size_t)b*256 + g)*4096);
    int m = kb*2 + (gcol >> 2);
    int cb = (gcol & 3)*64;
    const float4* R0 = reinterpret_cast<const float4*>(chg + (2*m)*256 + cb);
    const float4* R1 = reinterpret_cast<const float4*>(chg + (2*m+1)*256 + cb);
    float f0[16], f1[16];
#pragma unroll
    for (int u = 0; u < 4; u++) {
      *reinterpret_cast<float4*>(f0 + u*4) = R0[u];
      *reinterpret_cast<float4*>(f1 + u*4) = R1[u];
    }
    int bh = b*8 + (g >> 5);
    int c0l = (g & 31)*8;
    char* rowbase = out + (((size_t)bh*16 + kb)*256 + c0l)*64;
#pragma unroll
    for (int j = 0; j < 8; j++) {
      float ov[8];
#pragma unroll
      for (int u = 0; u < 8; u++)
        ov[u] = bj[j] + wj[j].x*f0[2*u] + wj[j].y*f0[2*u+1] + wj[j].z*f1[2*u] + wj[j].w*f1[2*u+1];
      int w0 = 0, w1 = 0;
      w0 = __builtin_amdgcn_cvt_pk_fp8_f32(ov[0], ov[1], w0, false);
      w0 = __builtin_amdgcn_cvt_pk_fp8_f32(ov[2], ov[3], w0, true);
      w1 = __builtin_amdgcn_cvt_pk_fp8_f32(ov[4], ov[5], w1, false);
      w1 = __builtin_amdgcn_cvt_pk_fp8_f32(ov[6], ov[7], w1, true);
      int2 st; st.x = w0; st.y = w1;
      *reinterpret_cast<int2*>(rowbase + j*64 + ((gcol ^ j)*8)) = st;
    }
  } else {
    // ---- v projection into swizzled chunk-transposed Vt (fp8, x8 scale)
    float* ch = reinterpret_cast<float*>(smem);
    int r = x - 256;
    int m = r & 31, h = r >> 5;
    {
      int seg = t >> 2, part = t & 3;
      int gl = seg >> 1, ky = seg & 1;
      const float* src = vin + (((size_t)b*256 + h*32 + gl)*64 + (2*m + ky))*64;
      float* drow = ch + (gl*2 + ky)*67;
#pragma unroll
      for (int i = 0; i < 4; i++) {
        float4 v = reinterpret_cast<const float4*>(src)[part + i*4];
        int x0 = (part + i*4)*4;
        drow[x0]=v.x; drow[x0+1]=v.y; drow[x0+2]=v.z; drow[x0+3]=v.w;
      }
    }
    int cgrp = t & 31, lgr = t >> 5;
    int c0 = cgrp*8;
    float4 wv8[8]; float bb8[8];
#pragma unroll
    for (int u = 0; u < 8; u++) {
      wv8[u] = reinterpret_cast<const float4*>(wv)[h*256 + c0 + u];
      bb8[u] = bv[h*256 + c0 + u];
    }
    __syncthreads();
    const float* r0 = ch + (cgrp*2 + 0)*67;
    const float* r1 = ch + (cgrp*2 + 1)*67;
    int bh = b*8 + h;
    char* base = Vt + ((size_t)bh*4 + (c0 >> 6))*65536;
    int gsw = ((cgrp & 7) ^ lgr)*8;
#pragma unroll
    for (int p = 0; p < 4; p++) {
      int n = p*8 + lgr;
      int l = m*32 + n;               // l&7 == lgr
      float c00 = r0[2*n], c01 = r0[2*n+1], c10 = r1[2*n], c11 = r1[2*n+1];
      float ov[8];
#pragma unroll
      for (int u = 0; u < 8; u++)
        ov[u] = 8.f*(bb8[u] + wv8[u].x*c00 + wv8[u].y*c01 + wv8[u].z*c10 + wv8[u].w*c11);
      int w0 = 0, w1 = 0;
      w0 = __builtin_amdgcn_cvt_pk_fp8_f32(ov[0], ov[1], w0, false);
      w0 = __builtin_amdgcn_cvt_pk_fp8_f32(ov[2], ov[3], w0, true);
      w1 = __builtin_amdgcn_cvt_pk_fp8_f32(ov[4], ov[5], w1, false);
      w1 = __builtin_amdgcn_cvt_pk_fp8_f32(ov[6], ov[7], w1, true);
      int2 st; st.x = w0; st.y = w1;
      *reinterpret_cast<int2*>(base + (size_t)l*64 + gsw) = st;
    }
  }
}

// ---------------- Kernel B: S = Q K^T (fp8 MFMA) + softmax -> Pattn (fp8 x32).
__global__ __launch_bounds__(256, 2) void attn_qk(
    const char* __restrict__ Pq, const char* __restrict__ Pk,
    char* __restrict__ Pattn) {
  int raw = blockIdx.x;
  int idx = raw >> 3;
  int bh = (raw & 7)*8 + (idx >> 2);   // 4 c-strips of one bh share an XCD
  int cs = idx & 3;
  int t = threadIdx.x, wave = t >> 6, lane = t & 63, lg = lane >> 4, lr = lane & 15;
  __shared__ __attribute__((aligned(16))) char smem[40960];
  char* Kb0 = smem;                    // 16 KB
  char* Kb1 = smem + 16384;            // 16 KB
  char* Qb0 = smem + 32768;            //  4 KB
  char* Qb1 = smem + 36864;            //  4 KB
  float (*red)[64] = reinterpret_cast<float (*)[64]>(smem + 32768);  // post-loop alias
  char* Pst = smem;                    // 16 KB post-loop alias
  const char* Kbase = Pk + (size_t)bh*262144 + wave*4096 + lane*16;
  const char* Qbase = Pq + (size_t)bh*262144 + (size_t)cs*4096 + wave*1024 + lane*16;
  char* Kd0 = Kb0 + wave*4096;  char* Kd1 = Kb1 + wave*4096;
  char* Qd0 = Qb0 + wave*1024;  char* Qd1 = Qb1 + wave*1024;

#define STAGE(kb, K_, Q_) { \
    const char* kc = Kbase + (size_t)(kb)*16384; \
    _Pragma("unroll") \
    for (int i_ = 0; i_ < 4; i_++) gload16(kc + i_*1024, (K_) + i_*1024); \
    gload16(Qbase + (size_t)(kb)*16384, (Q_)); }

  f32x4 acc[4][4];
#pragma unroll
  for (int i = 0; i < 4; i++)
#pragma unroll
    for (int j = 0; j < 4; j++) { f32x4 z = {0.f,0.f,0.f,0.f}; acc[i][j] = z; }

  STAGE(0, Kd0, Qd0);
#pragma unroll
  for (int kb = 0; kb < 16; kb++) {
    if (kb < 15) {
      if (kb & 1) { STAGE(kb+1, Kd0, Qd0); } else { STAGE(kb+1, Kd1, Qd1); }
      asm volatile("s_waitcnt vmcnt(5)" ::: "memory");   // prev chunk complete
    } else {
      asm volatile("s_waitcnt vmcnt(0)" ::: "memory");
    }
    __builtin_amdgcn_s_barrier();
    __builtin_amdgcn_sched_barrier(0);
    const char* Kc = (kb & 1) ? Kb1 : Kb0;
    const char* Qc = (kb & 1) ? Qb1 : Qb0;
#pragma unroll
    for (int ks = 0; ks < 2; ks++) {
      int colx = (ks*32 + lg*8) ^ ((lr & 7) << 3);
      i64 a[4];
#pragma unroll
      for (int mi = 0; mi < 4; mi++)
        a[mi] = *reinterpret_cast<const i64*>(Qc + (mi*16 + lr)*64 + colx);
#pragma unroll
      for (int ni = 0; ni < 4; ni++) {
        i64 bfr = *reinterpret_cast<const i64*>(Kc + (wave*64 + ni*16 + lr)*64 + colx);
#pragma unroll
        for (int mi = 0; mi < 4; mi++)
          acc[mi][ni] = __builtin_amdgcn_mfma_f32_16x16x32_fp8_fp8(a[mi], bfr, acc[mi][ni], 0, 0, 0);
      }
    }
    __builtin_amdgcn_s_barrier();        // all reads of this buffer done
    __builtin_amdgcn_sched_barrier(0);
  }
#undef STAGE
  // softmax over d (wave holds 64 d; combine 4 waves via red[4][64])
  const float scale = 0.03125f;
  float sums[4][4];
#pragma unroll
  for (int mi = 0; mi < 4; mi++)
#pragma unroll
    for (int r = 0; r < 4; r++) {
      float mx = fmaxf(fmaxf(acc[mi][0][r], acc[mi][1][r]), fmaxf(acc[mi][2][r], acc[mi][3][r]));
#pragma unroll
      for (int off = 1; off < 16; off <<= 1) mx = fmaxf(mx, __shfl_xor(mx, off, 64));
      red[wave][mi*16 + lg*4 + r] = mx;
    }
  __syncthreads();
#pragma unroll
  for (int mi = 0; mi < 4; mi++)
#pragma unroll
    for (int r = 0; r < 4; r++) {
      int clr = mi*16 + lg*4 + r;
      float mx = fmaxf(fmaxf(red[0][clr], red[1][clr]), fmaxf(red[2][clr], red[3][clr]));
      float s = 0.f;
#pragma unroll
      for (int ni = 0; ni < 4; ni++) {
        float p = __expf(scale*(acc[mi][ni][r] - mx));
        acc[mi][ni][r] = p; s += p;
      }
#pragma unroll
      for (int off = 1; off < 16; off <<= 1) s += __shfl_xor(s, off, 64);
      sums[mi][r] = s;
    }
  __syncthreads();
#pragma unroll
  for (int mi = 0; mi < 4; mi++)
#pragma unroll
    for (int r = 0; r < 4; r++) red[wave][mi*16 + lg*4 + r] = sums[mi][r];
  __syncthreads();
  // normalize (x32) + stage P strip into LDS as fp8, swizzled layout
#pragma unroll
  for (int mi = 0; mi < 4; mi++)
#pragma unroll
    for (int r = 0; r < 4; r++) {
      int clr = mi*16 + lg*4 + r;
      float iv = 32.f/(red[0][clr] + red[1][clr] + red[2][clr] + red[3][clr]);
      char* prow = Pst + wave*4096 + clr*64;
      int xr = (clr & 7) << 3;
#pragma unroll
      for (int ni = 0; ni < 4; ni += 2) {
        int pk2 = __builtin_amdgcn_cvt_pk_fp8_f32(acc[mi][ni][r]*iv, acc[mi][ni+1][r]*iv, 0, false);
        prow[(ni*16 + lr) ^ xr]     = (char)(pk2 & 0xff);
        prow[((ni+1)*16 + lr) ^ xr] = (char)((pk2 >> 8) & 0xff);
      }
    }
  __syncthreads();
  // coalesced copy-out: 16 KB total; Pattn chunk kb gets rows cs*64..+64
  const uint4* ls = reinterpret_cast<const uint4*>(Pst);
#pragma unroll
  for (int i = 0; i < 4; i++) {
    int f = i*256 + t;              // 1024 uint4
    int kb = f >> 8, rem = f & 255;
    char* dst = Pattn + ((size_t)(bh*4 + kb)*256 + cs*64)*64 + (size_t)rem*16;
    *reinterpret_cast<uint4*>(dst) = ls[f];
  }
}

// ---------------- Kernel C: O = Pattn * V (fp8 MFMA), fused deconv + residual
__global__ __launch_bounds__(256, 4) void pv_deconv(const char* __restrict__ Pattn,
    const char* __restrict__ Vt, const float* __restrict__ qin,
    const float* __restrict__ wo, const float* __restrict__ bo,
    const float* __restrict__ gamma, float* __restrict__ outp) {
  int raw = blockIdx.x;
  int idx = raw >> 3;
  int pair = (raw & 7)*32 + (idx >> 2);   // (mb,bh); 4 tb-blocks share V chunk + XCD
  int tb = idx & 3;
  int mb = pair & 3, bh = pair >> 2;
  int h = bh & 7, b = bh >> 3;
  int t = threadIdx.x, wave = t >> 6, lane = t & 63, lg = lane >> 4, lr = lane & 15;
  __shared__ __attribute__((aligned(16))) char smem[40960];
  char* Pl   = smem;                                     // 4096 B
  char* Vl   = smem + 4096;                              // 16384 B
  bf16* OlT  = reinterpret_cast<bf16*>(smem);            // 256*66*2 = 33792 B (post-loop)
  float* wo_s = reinterpret_cast<float*>(smem + 36864);  // 1024 B (post-loop)
  float* bo_s = reinterpret_cast<float*>(smem + 37888);  // 32 B
  const char* Pbase = Pattn + (size_t)bh*65536 + tb*4096;
  const char* Vbase = Vt + (size_t)bh*262144 + mb*16384;
  f32x4 acc[4][4];
#pragma unroll
  for (int i = 0; i < 4; i++)
#pragma unroll
    for (int j = 0; j < 4; j++) { f32x4 z = {0.f,0.f,0.f,0.f}; acc[i][j] = z; }
  for (int kb = 0; kb < 4; kb++) {
    __syncthreads();
    {
      const char* pc = Pbase + (size_t)kb*16384 + wave*1024 + lane*16;
      gload16(pc, Pl + wave*1024);
      const char* vc = Vbase + (size_t)kb*65536 + wave*4096 + lane*16;
      char* vl = Vl + wave*4096;
#pragma unroll
      for (int i = 0; i < 4; i++) gload16(vc + i*1024, vl + i*1024);
    }
    __syncthreads();
#pragma unroll
    for (int ks = 0; ks < 2; ks++) {
      int colx = (ks*32 + lg*8) ^ ((lr & 7) << 3);
      i64 a[4];
#pragma unroll
      for (int mi = 0; mi < 4; mi++)
        a[mi] = *reinterpret_cast<const i64*>(Pl + (mi*16 + lr)*64 + colx);
#pragma unroll
      for (int ni = 0; ni < 4; ni++) {
        i64 bfr = *reinterpret_cast<const i64*>(Vl + (wave*64 + ni*16 + lr)*64 + colx);
#pragma unroll
        for (int mi = 0; mi < 4; mi++)
          acc[mi][ni] = __builtin_amdgcn_mfma_f32_16x16x32_fp8_fp8(a[mi], bfr, acc[mi][ni], 0, 0, 0);
      }
    }
  }
  __syncthreads();   // all MFMA LDS reads done before OlT/wo_s overwrite
  const float rescale = 1.f/256.f;   // undo P*32 and V*8
#pragma unroll
  for (int mi = 0; mi < 4; mi++)
#pragma unroll
    for (int ni = 0; ni < 4; ni++) {
      int l = wave*64 + ni*16 + lr;
      int cb = mi*16 + lg*4;
      bf16x4 p;
      p[0] = (bf16)(acc[mi][ni][0]*rescale); p[1] = (bf16)(acc[mi][ni][1]*rescale);
      p[2] = (bf16)(acc[mi][ni][2]*rescale); p[3] = (bf16)(acc[mi][ni][3]*rescale);
      *reinterpret_cast<bf16x4*>(OlT + l*66 + cb) = p;
    }
  wo_s[t] = wo[((size_t)(h*32 + tb*8 + (t>>5)))*32 + (t & 31)];
  if (t < 8) bo_s[t] = bo[h*32 + tb*8 + t];
  __syncthreads();
  // epilogue: deconv 2x2 stride 2 + bias + residual; fully coalesced float4 I/O
  int xq = t & 15, b5 = (t >> 4) & 1, ct = t >> 5;
  float2 wp[8];
#pragma unroll
  for (int j = 0; j < 8; j++)
    wp[j] = *reinterpret_cast<const float2*>(wo_s + ct*32 + j*4 + (1 - b5)*2);
  float bias = bo_s[ct];
  float gm = gamma[0];
  int co = h*32 + tb*8 + ct;
#pragma unroll
  for (int it = 0; it < 8; it++) {
    int y = it*2 + b5;
    int ll0 = it*32 + xq*2;
    bf16x4 o00 = *reinterpret_cast<const bf16x4*>(OlT + ll0*66 + ct*8);
    bf16x4 o01 = *reinterpret_cast<const bf16x4*>(OlT + ll0*66 + ct*8 + 4);
    bf16x4 o10 = *reinterpret_cast<const bf16x4*>(OlT + (ll0+1)*66 + ct*8);
    bf16x4 o11 = *reinterpret_cast<const bf16x4*>(OlT + (ll0+1)*66 + ct*8 + 4);
    float v0 = bias, v1 = bias, v2 = bias, v3 = bias;
#pragma unroll
    for (int j = 0; j < 4; j++) {
      float f0 = (float)o00[j], f1 = (float)o01[j];
      v0 += f0*wp[j].y;   v1 += f0*wp[j].x;
      v0 += f1*wp[4+j].y; v1 += f1*wp[4+j].x;
      float g0 = (float)o10[j], g1 = (float)o11[j];
      v2 += g0*wp[j].y;   v3 += g0*wp[j].x;
      v2 += g1*wp[4+j].y; v3 += g1*wp[4+j].x;
    }
    size_t oi = (((size_t)b*256 + co)*64 + (mb*16 + y))*64 + xq*4;
    float4 qv = *reinterpret_cast<const float4*>(qin + oi);
    float4 ov;
    ov.x = qv.x + gm*v0; ov.y = qv.y + gm*v1;
    ov.z = qv.z + gm*v2; ov.w = qv.w + gm*v3;
    *reinterpret_cast<float4*>(outp + oi) = ov;
  }
}

extern "C" void kernel_launch(void* const* d_in, const int* in_sizes, int n_in,
                              void* d_out, int out_size, void* d_ws, size_t ws_size,
                              hipStream_t stream) {
  const float* q  = (const float*)d_in[0];
  const float* k  = (const float*)d_in[1];
  const float* v  = (const float*)d_in[2];
  const float* wq = (const float*)d_in[3];
  const float* bq = (const float*)d_in[4];
  const float* wk = (const float*)d_in[5];
  const float* bk = (const float*)d_in[6];
  const float* wv = (const float*)d_in[7];
  const float* bv = (const float*)d_in[8];
  const float* wo = (const float*)d_in[9];
  const float* bo = (const float*)d_in[10];
  const float* gamma = (const float*)d_in[11];
  float* out = (float*)d_out;

  char* ws = (char*)d_ws;
  char* Pk    = ws;                  //  16,777,216 B (fp8)
  char* Pq    = ws + 16777216;       //  16,777,216 B (fp8)
  char* Vt    = ws + 33554432;       //  16,777,216 B (fp8, x8)
  char* Pattn = ws + 50331648;       //   4,194,304 B (fp8, x32)

  proj_kqv<<<dim3(512, 8), 256, 0, stream>>>(k, q, v, wk, bk, wq, bq, wv, bv, Pk, Pq, Vt);
  attn_qk <<<dim3(256), 256, 0, stream>>>(Pq, Pk, Pattn);
  pv_deconv<<<dim3(1024), 256, 0, stream>>>(Pattn, Vt, q, wo, bo, gamma, out);
}